// Round 1
// baseline (339.073 us; speedup 1.0000x reference)
//
#include <hip/hip_runtime.h>
#include <math.h>

#define C_ 256
#define HW_ 4096
#define PLANE (C_*HW_)   // 1048576 floats per batch

// ---------------------------------------------------------------------------
// GEMM body: Y[o,n] = sum_c W[o,c] * X[c,n] (+bias), one batch slice.
// 64x64 output tile, K-chunks of 16, 256 threads, 4x4 accum per thread.
// ---------------------------------------------------------------------------
__device__ __forceinline__ void gemm_body(const float* __restrict__ W,
                                          const float* __restrict__ X,
                                          const float* __restrict__ bias,
                                          float* __restrict__ Y)
{
    __shared__ float As[16][64];   // [k][m]
    __shared__ float Bs[16][64];   // [k][n]
    const int t  = threadIdx.x;
    const int n0 = blockIdx.x * 64;
    const int m0 = blockIdx.y * 64;
    const int tx = t & 15, ty = t >> 4;
    const int lm = t >> 2, lk = (t & 3) * 4;   // W-tile load coords
    const int bk = t >> 4, bn = (t & 15) * 4;  // X-tile load coords

    float acc[4][4];
#pragma unroll
    for (int i = 0; i < 4; i++)
#pragma unroll
        for (int j = 0; j < 4; j++) acc[i][j] = 0.f;

    for (int k0 = 0; k0 < C_; k0 += 16) {
        float4 wv4 = *(const float4*)&W[(m0 + lm) * C_ + k0 + lk];
        float4 xv4 = *(const float4*)&X[(size_t)(k0 + bk) * HW_ + n0 + bn];
        __syncthreads();
        As[lk + 0][lm] = wv4.x;
        As[lk + 1][lm] = wv4.y;
        As[lk + 2][lm] = wv4.z;
        As[lk + 3][lm] = wv4.w;
        *(float4*)&Bs[bk][bn] = xv4;
        __syncthreads();
#pragma unroll
        for (int kk = 0; kk < 16; ++kk) {
            float4 a = *(const float4*)&As[kk][ty * 4];
            float4 b = *(const float4*)&Bs[kk][tx * 4];
            acc[0][0] += a.x * b.x; acc[0][1] += a.x * b.y; acc[0][2] += a.x * b.z; acc[0][3] += a.x * b.w;
            acc[1][0] += a.y * b.x; acc[1][1] += a.y * b.y; acc[1][2] += a.y * b.z; acc[1][3] += a.y * b.w;
            acc[2][0] += a.z * b.x; acc[2][1] += a.z * b.y; acc[2][2] += a.z * b.z; acc[2][3] += a.z * b.w;
            acc[3][0] += a.w * b.x; acc[3][1] += a.w * b.y; acc[3][2] += a.w * b.z; acc[3][3] += a.w * b.w;
        }
    }
#pragma unroll
    for (int i = 0; i < 4; i++) {
        float bb = bias ? bias[m0 + ty * 4 + i] : 0.f;
        float4 r = make_float4(acc[i][0] + bb, acc[i][1] + bb, acc[i][2] + bb, acc[i][3] + bb);
        *(float4*)&Y[(size_t)(m0 + ty * 4 + i) * HW_ + n0 + tx * 4] = r;
    }
}

// q/k/v projections: grid.z = batch(4) * which(3)
__global__ __launch_bounds__(256) void gemm_qkv_kernel(
    const float* __restrict__ x,
    const float* __restrict__ wq, const float* __restrict__ wk, const float* __restrict__ wvw,
    float* __restrict__ q, float* __restrict__ k, float* __restrict__ v)
{
    int z = blockIdx.z;
    int batch = z & 3, which = z >> 2;
    const float* W = (which == 0) ? wq : (which == 1) ? wk : wvw;
    float* Y = (which == 0) ? q : (which == 1) ? k : v;
    gemm_body(W, x + (size_t)batch * PLANE, nullptr, Y + (size_t)batch * PLANE);
}

// final projection with bias
__global__ __launch_bounds__(256) void gemm_out_kernel(
    const float* __restrict__ xin, const float* __restrict__ wp,
    const float* __restrict__ bp, float* __restrict__ y)
{
    int batch = blockIdx.z;
    gemm_body(wp, xin + (size_t)batch * PLANE, bp, y + (size_t)batch * PLANE);
}

// ---------------------------------------------------------------------------
// GroupNorm stats: one block per (tensor, b, g); 32 ch x 4096 px = 131072 el.
// grid 64 -> t0 (blocks 0..31) and t1 (32..63); grid 32 -> t0 only.
// stats[blk*2] = mean, stats[blk*2+1] = rstd
// ---------------------------------------------------------------------------
__global__ __launch_bounds__(256) void gn_stats_kernel(
    const float* __restrict__ t0, const float* __restrict__ t1, float* __restrict__ stats)
{
    int blk = blockIdx.x;
    const float* src = (blk < 32) ? t0 : t1;
    int bg = blk & 31;
    const float* base = src + (size_t)(bg >> 3) * PLANE + (size_t)(bg & 7) * 32 * HW_;
    int t = threadIdx.x;
    float s = 0.f, ss = 0.f;
    for (int c = 0; c < 32; c++) {
        const float* row = base + (size_t)c * HW_;
#pragma unroll
        for (int i = 0; i < 4; i++) {
            float4 v4 = *(const float4*)&row[(i * 256 + t) * 4];
            s  += v4.x + v4.y + v4.z + v4.w;
            ss += v4.x * v4.x + v4.y * v4.y + v4.z * v4.z + v4.w * v4.w;
        }
    }
#pragma unroll
    for (int off = 32; off >= 1; off >>= 1) {
        s  += __shfl_down(s, off);
        ss += __shfl_down(ss, off);
    }
    __shared__ float red[8];
    int wave = t >> 6;
    if ((t & 63) == 0) { red[wave * 2] = s; red[wave * 2 + 1] = ss; }
    __syncthreads();
    if (t == 0) {
        float S = 0.f, SS = 0.f;
        for (int w = 0; w < 4; w++) { S += red[w * 2]; SS += red[w * 2 + 1]; }
        float mean = S * (1.f / 131072.f);
        float var  = SS * (1.f / 131072.f) - mean * mean;
        stats[blk * 2 + 0] = mean;
        stats[blk * 2 + 1] = rsqrtf(var + 1e-5f);
    }
}

// ---------------------------------------------------------------------------
// Per-pixel spectral attention. Block = 256 threads (thread = channel),
// 16 pixels per block. GN affine fused on q,k loads; L2 norm via shuffles.
// out[d] = sum_e exp(qn_d*scale*kn_e)*v_e / sum_e exp(qn_d*scale*kn_e)
// ---------------------------------------------------------------------------
__global__ __launch_bounds__(256) void attn_kernel(
    const float* __restrict__ qraw, const float* __restrict__ kraw, const float* __restrict__ vin,
    const float* __restrict__ stats,   // [0:64) q (mean,rstd)x32 ; [64:128) k
    const float* __restrict__ gqg, const float* __restrict__ gqb,
    const float* __restrict__ gkg, const float* __restrict__ gkb,
    float* __restrict__ out)
{
    __shared__ float ksm[16 * 256];  // [p][c] normalized k
    __shared__ float vsm[16 * 256];  // [p][c] v
    const int t = threadIdx.x;               // channel
    const int blk = blockIdx.x;              // 1024 blocks
    const int b = blk >> 8;
    const int hw0 = (blk & 255) * 16;
    const size_t base = (size_t)b * PLANE + (size_t)t * HW_ + hw0;
    const int g = t >> 5;
    const int sg = (b * 8 + g) * 2;

    // ---- K: load, GN affine, normalize, stage to LDS ----
    {
        float m = stats[64 + sg], r = stats[64 + sg + 1];
        float ga = r * gkg[t];
        float be = gkb[t] - m * ga;
        float kv[16];
        const float4* kp = (const float4*)(kraw + base);
#pragma unroll
        for (int i = 0; i < 4; i++) {
            float4 k4 = kp[i];
            kv[4 * i + 0] = k4.x * ga + be;
            kv[4 * i + 1] = k4.y * ga + be;
            kv[4 * i + 2] = k4.z * ga + be;
            kv[4 * i + 3] = k4.w * ga + be;
        }
#pragma unroll
        for (int p = 0; p < 16; p++) {
            float sk = kv[p] * kv[p];
#pragma unroll
            for (int mm = 1; mm < 32; mm <<= 1) sk += __shfl_xor(sk, mm);
            float inv = 1.f / fmaxf(sqrtf(sk), 1e-12f);
            ksm[p * 256 + t] = kv[p] * inv;
        }
    }
    // ---- V: stage to LDS ----
    {
        const float4* vp = (const float4*)(vin + base);
#pragma unroll
        for (int i = 0; i < 4; i++) {
            float4 v4 = vp[i];
            vsm[(4 * i + 0) * 256 + t] = v4.x;
            vsm[(4 * i + 1) * 256 + t] = v4.y;
            vsm[(4 * i + 2) * 256 + t] = v4.z;
            vsm[(4 * i + 3) * 256 + t] = v4.w;
        }
    }
    // ---- Q: load, GN affine, normalize (kept in registers) ----
    float an[16];
    {
        float m = stats[sg], r = stats[sg + 1];
        float ga = r * gqg[t];
        float be = gqb[t] - m * ga;
        float qv[16];
        const float4* qp = (const float4*)(qraw + base);
#pragma unroll
        for (int i = 0; i < 4; i++) {
            float4 q4 = qp[i];
            qv[4 * i + 0] = q4.x * ga + be;
            qv[4 * i + 1] = q4.y * ga + be;
            qv[4 * i + 2] = q4.z * ga + be;
            qv[4 * i + 3] = q4.w * ga + be;
        }
#pragma unroll
        for (int p = 0; p < 16; p++) {
            float sq = qv[p] * qv[p];
#pragma unroll
            for (int mm = 1; mm < 32; mm <<= 1) sq += __shfl_xor(sq, mm);
            float inv = 1.f / fmaxf(sqrtf(sq), 1e-12f);
            an[p] = qv[p] * inv * 0.17677669529663687f;  // qn_d * scale
        }
    }
    __syncthreads();
    // ---- attention ----
    const int hbase = (t >> 5) * 32;
    float outp[16];
#pragma unroll
    for (int p = 0; p < 16; p++) {
        const float* ksp = ksm + p * 256 + hbase;
        const float* vsp = vsm + p * 256 + hbase;
        float a = an[p], num = 0.f, den = 0.f;
#pragma unroll
        for (int e = 0; e < 32; e++) {
            float w = __expf(a * ksp[e]);
            den += w;
            num += w * vsp[e];
        }
        outp[p] = num / den;
    }
    float4* op = (float4*)(out + base);
#pragma unroll
    for (int i = 0; i < 4; i++)
        op[i] = make_float4(outp[4 * i], outp[4 * i + 1], outp[4 * i + 2], outp[4 * i + 3]);
}

// ---------------------------------------------------------------------------
// Depthwise 3x3 stencils
// ---------------------------------------------------------------------------
__device__ __forceinline__ float gelu_exact(float v) {
    return 0.5f * v * (1.f + erff(v * 0.70710678118654752f));
}

__global__ __launch_bounds__(256) void dwconv1_kernel(
    const float* __restrict__ x, const float* __restrict__ w9,
    const float* __restrict__ bias, float* __restrict__ out)
{
    int idx = blockIdx.x * 256 + threadIdx.x;       // 4*256*4096 total
    int xx = idx & 63, yy = (idx >> 6) & 63, c = (idx >> 12) & 255;
    const float* plane = x + (idx & ~4095);
    const float* wc = w9 + c * 9;
    float s = bias[c];
#pragma unroll
    for (int ky = 0; ky < 3; ky++) {
        int y2 = yy + ky - 1;
        if ((unsigned)y2 < 64u) {
#pragma unroll
            for (int kx = 0; kx < 3; kx++) {
                int x2 = xx + kx - 1;
                if ((unsigned)x2 < 64u) s += wc[ky * 3 + kx] * plane[y2 * 64 + x2];
            }
        }
    }
    out[idx] = gelu_exact(s);
}

__global__ __launch_bounds__(256) void dwconv2_add_kernel(
    const float* __restrict__ p1, const float* __restrict__ w9,
    const float* __restrict__ bias, float* __restrict__ io)
{
    int idx = blockIdx.x * 256 + threadIdx.x;
    int xx = idx & 63, yy = (idx >> 6) & 63, c = (idx >> 12) & 255;
    const float* plane = p1 + (idx & ~4095);
    const float* wc = w9 + c * 9;
    float s = bias[c];
#pragma unroll
    for (int ky = 0; ky < 3; ky++) {
        int y2 = yy + ky - 1;
        if ((unsigned)y2 < 64u) {
#pragma unroll
            for (int kx = 0; kx < 3; kx++) {
                int x2 = xx + kx - 1;
                if ((unsigned)x2 < 64u) s += wc[ky * 3 + kx] * plane[y2 * 64 + x2];
            }
        }
    }
    io[idx] += s;
}

// ---------------------------------------------------------------------------
// Final GroupNorm apply (in place on d_out), float4 per thread
// ---------------------------------------------------------------------------
__global__ __launch_bounds__(256) void gn_apply_kernel(
    float* __restrict__ y, const float* __restrict__ stats,
    const float* __restrict__ gamma, const float* __restrict__ beta)
{
    int i4 = blockIdx.x * 256 + threadIdx.x;   // 1048576 float4s -> 4096 blocks
    int idx = i4 * 4;
    int c = (idx >> 12) & 255;
    int bg = ((idx >> 20) << 3) | (c >> 5);
    float mean = stats[128 + bg * 2], rstd = stats[128 + bg * 2 + 1];
    float ga = rstd * gamma[c], be = beta[c] - mean * ga;
    float4 v4 = *(float4*)&y[idx];
    v4.x = v4.x * ga + be;
    v4.y = v4.y * ga + be;
    v4.z = v4.z * ga + be;
    v4.w = v4.w * ga + be;
    *(float4*)&y[idx] = v4;
}

// ---------------------------------------------------------------------------
extern "C" void kernel_launch(void* const* d_in, const int* in_sizes, int n_in,
                              void* d_out, int out_size, void* d_ws, size_t ws_size,
                              hipStream_t stream)
{
    const float* x   = (const float*)d_in[0];
    const float* wq  = (const float*)d_in[1];
    const float* gqg = (const float*)d_in[2];
    const float* gqb = (const float*)d_in[3];
    const float* wk  = (const float*)d_in[4];
    const float* gkg = (const float*)d_in[5];
    const float* gkb = (const float*)d_in[6];
    const float* wv  = (const float*)d_in[7];
    const float* wp  = (const float*)d_in[8];
    const float* bp  = (const float*)d_in[9];
    const float* gpg = (const float*)d_in[10];
    const float* gpb = (const float*)d_in[11];
    const float* dw1 = (const float*)d_in[12];
    const float* db1 = (const float*)d_in[13];
    const float* dw2 = (const float*)d_in[14];
    const float* db2 = (const float*)d_in[15];
    float* out = (float*)d_out;

    float* ws    = (float*)d_ws;
    float* qraw  = ws;
    float* kraw  = ws + (size_t)4194304;
    float* vbuf  = ws + (size_t)2 * 4194304;
    float* abuf  = ws + (size_t)3 * 4194304;
    float* pos1  = ws;                       // reuse qraw (attention already done)
    float* stats = ws + (size_t)4 * 4194304; // 192 floats: q[0:64) k[64:128) out[128:192)

    dim3 blk(256);
    gemm_qkv_kernel<<<dim3(64, 4, 12), blk, 0, stream>>>(x, wq, wk, wv, qraw, kraw, vbuf);
    gn_stats_kernel<<<dim3(64), blk, 0, stream>>>(qraw, kraw, stats);
    attn_kernel<<<dim3(1024), blk, 0, stream>>>(qraw, kraw, vbuf, stats,
                                                gqg, gqb, gkg, gkb, abuf);
    dwconv1_kernel<<<dim3(16384), blk, 0, stream>>>(x, dw1, db1, pos1);
    dwconv2_add_kernel<<<dim3(16384), blk, 0, stream>>>(pos1, dw2, db2, abuf);
    gemm_out_kernel<<<dim3(64, 4, 4), blk, 0, stream>>>(abuf, wp, bp, out);
    gn_stats_kernel<<<dim3(32), blk, 0, stream>>>(out, out, stats + 128);
    gn_apply_kernel<<<dim3(4096), blk, 0, stream>>>(out, stats, gpg, gpb);
}

// Round 2
// 257.534 us; speedup vs baseline: 1.3166x; 1.3166x over previous
//
#include <hip/hip_runtime.h>
#include <math.h>
#include <stdint.h>

#define C_ 256
#define HW_ 4096
#define PLANE (C_*HW_)   // 1048576 elements per batch

typedef __attribute__((ext_vector_type(8))) short bf16x8;
typedef __attribute__((ext_vector_type(4))) float f32x4;

__device__ __forceinline__ unsigned short f2bf(float f) {
    union { float f; unsigned int u; } v; v.f = f;
    unsigned int r = v.u + 0x7fffu + ((v.u >> 16) & 1u);
    return (unsigned short)(r >> 16);
}

__device__ __forceinline__ void load_lds16(const void* g, void* l) {
    __builtin_amdgcn_global_load_lds(
        (const __attribute__((address_space(1))) unsigned int*)g,
        (__attribute__((address_space(3))) unsigned int*)l, 16, 0, 0);
}

// ---------------------------------------------------------------------------
// Weight convert: wq,wk,wv,wp (each 256x256 fp32, [o][c] K-contig) -> bf16
// ---------------------------------------------------------------------------
__global__ __launch_bounds__(256) void wcvt_kernel(
    const float* __restrict__ wq, const float* __restrict__ wk,
    const float* __restrict__ wv, const float* __restrict__ wp,
    unsigned short* __restrict__ dst)
{
    int idx = blockIdx.x * 256 + threadIdx.x;   // 262144 total
    const float* s = (idx < 65536) ? wq : (idx < 131072) ? wk
                   : (idx < 196608) ? wv : wp;
    dst[idx] = f2bf(s[idx & 65535]);
}

// ---------------------------------------------------------------------------
// Transpose + convert: src fp32 [b][256][4096] -> dst bf16 [b][4096][256]
// 64x64 tiles through LDS; grid (64, 4, 4)
// ---------------------------------------------------------------------------
__global__ __launch_bounds__(256) void transpose_cvt_kernel(
    const float* __restrict__ src, unsigned short* __restrict__ dst)
{
    __shared__ float tile[64][65];
    int b = blockIdx.z;
    const float* s = src + (size_t)b * PLANE;
    unsigned short* d = dst + (size_t)b * PLANE;
    int c0 = blockIdx.y * 64, n0 = blockIdx.x * 64;
    int t = threadIdx.x;
    int r = t >> 6, col = t & 63;
#pragma unroll
    for (int i = 0; i < 16; i++)
        tile[r + i * 4][col] = s[(size_t)(c0 + r + i * 4) * HW_ + n0 + col];
    __syncthreads();
#pragma unroll
    for (int i = 0; i < 16; i++)
        d[(size_t)(n0 + r + i * 4) * 256 + c0 + col] = f2bf(tile[col][r + i * 4]);
}

// ---------------------------------------------------------------------------
// MFMA GEMM: Y[o][n] = sum_c W[o][c] * Xt[n][c]  (both operands K-contig bf16)
// 128x128 tile, BK=32, 4 waves x (4x4 frags of 16x16x32), global_load_lds.
// ---------------------------------------------------------------------------
__device__ __forceinline__ void mfma_gemm_body(
    const unsigned short* __restrict__ W,    // 256 x 256 bf16
    const unsigned short* __restrict__ Xt,   // 4096 x 256 bf16
    const float* __restrict__ bias,          // may be null
    float* __restrict__ Y)                   // 256 x 4096 fp32
{
    __shared__ unsigned short As[128 * 32];
    __shared__ unsigned short Bs[128 * 32];
    const int t = threadIdx.x;
    const int lane = t & 63, wave = t >> 6;
    const int n0 = blockIdx.x * 128;
    const int m0 = blockIdx.y * 128;

    f32x4 acc[4][4];
#pragma unroll
    for (int i = 0; i < 4; i++)
#pragma unroll
        for (int j = 0; j < 4; j++) acc[i][j] = (f32x4)0.f;

    // staging: each wave covers 32 rows via 2 insts of 16 rows (64 lanes x 16B)
    const int srow = wave * 32 + (lane >> 2);
    const int scol = (lane & 3) * 8;
    const unsigned short* ga = W  + (size_t)(m0 + srow) * 256 + scol;
    const unsigned short* gb = Xt + (size_t)(n0 + srow) * 256 + scol;
    unsigned short* la = As + (wave * 32) * 32;
    unsigned short* lb = Bs + (wave * 32) * 32;

    const int wm = wave >> 1, wn = wave & 1;
    const int fr = lane & 15, kg = lane >> 4;

    for (int k0 = 0; k0 < 256; k0 += 32) {
        if (k0) __syncthreads();
        load_lds16(ga + k0,             la);
        load_lds16(ga + k0 + 16 * 256,  la + 16 * 32);
        load_lds16(gb + k0,             lb);
        load_lds16(gb + k0 + 16 * 256,  lb + 16 * 32);
        __syncthreads();   // drains vmcnt -> LDS valid

        bf16x8 af[4], bfr[4];
#pragma unroll
        for (int i = 0; i < 4; i++) {
            af[i]  = *(const bf16x8*)(As + (wm * 64 + i * 16 + fr) * 32 + kg * 8);
            bfr[i] = *(const bf16x8*)(Bs + (wn * 64 + i * 16 + fr) * 32 + kg * 8);
        }
#pragma unroll
        for (int mi = 0; mi < 4; mi++)
#pragma unroll
            for (int ni = 0; ni < 4; ni++)
                acc[mi][ni] = __builtin_amdgcn_mfma_f32_16x16x32_bf16(
                    af[mi], bfr[ni], acc[mi][ni], 0, 0, 0);
    }

    // epilogue: D col = lane&15, row = (lane>>4)*4 + reg   [m89-verified]
    const int cl = lane & 15, q = lane >> 4;
#pragma unroll
    for (int mi = 0; mi < 4; mi++) {
#pragma unroll
        for (int r = 0; r < 4; r++) {
            int grow = m0 + wm * 64 + mi * 16 + q * 4 + r;
            float bb = bias ? bias[grow] : 0.f;
#pragma unroll
            for (int ni = 0; ni < 4; ni++) {
                int gcol = n0 + wn * 64 + ni * 16 + cl;
                Y[(size_t)grow * HW_ + gcol] = acc[mi][ni][r] + bb;
            }
        }
    }
}

__global__ __launch_bounds__(256) void gemm_qkv_mfma(
    const unsigned short* __restrict__ wbf, const unsigned short* __restrict__ xT,
    float* __restrict__ q, float* __restrict__ k, float* __restrict__ v)
{
    int z = blockIdx.z;
    int batch = z & 3, which = z >> 2;
    const unsigned short* W = wbf + which * 65536;
    float* Y = (which == 0) ? q : (which == 1) ? k : v;
    mfma_gemm_body(W, xT + (size_t)batch * PLANE, nullptr, Y + (size_t)batch * PLANE);
}

__global__ __launch_bounds__(256) void gemm_out_mfma(
    const unsigned short* __restrict__ wbf, const unsigned short* __restrict__ aT,
    const float* __restrict__ bp, float* __restrict__ y)
{
    int batch = blockIdx.z;
    mfma_gemm_body(wbf + 3 * 65536, aT + (size_t)batch * PLANE, bp,
                   y + (size_t)batch * PLANE);
}

// ---------------------------------------------------------------------------
// GroupNorm stats (unchanged from round 1)
// ---------------------------------------------------------------------------
__global__ __launch_bounds__(256) void gn_stats_kernel(
    const float* __restrict__ t0, const float* __restrict__ t1, float* __restrict__ stats)
{
    int blk = blockIdx.x;
    const float* src = (blk < 32) ? t0 : t1;
    int bg = blk & 31;
    const float* base = src + (size_t)(bg >> 3) * PLANE + (size_t)(bg & 7) * 32 * HW_;
    int t = threadIdx.x;
    float s = 0.f, ss = 0.f;
    for (int c = 0; c < 32; c++) {
        const float* row = base + (size_t)c * HW_;
#pragma unroll
        for (int i = 0; i < 4; i++) {
            float4 v4 = *(const float4*)&row[(i * 256 + t) * 4];
            s  += v4.x + v4.y + v4.z + v4.w;
            ss += v4.x * v4.x + v4.y * v4.y + v4.z * v4.z + v4.w * v4.w;
        }
    }
#pragma unroll
    for (int off = 32; off >= 1; off >>= 1) {
        s  += __shfl_down(s, off);
        ss += __shfl_down(ss, off);
    }
    __shared__ float red[8];
    int wave = t >> 6;
    if ((t & 63) == 0) { red[wave * 2] = s; red[wave * 2 + 1] = ss; }
    __syncthreads();
    if (t == 0) {
        float S = 0.f, SS = 0.f;
        for (int w = 0; w < 4; w++) { S += red[w * 2]; SS += red[w * 2 + 1]; }
        float mean = S * (1.f / 131072.f);
        float var  = SS * (1.f / 131072.f) - mean * mean;
        stats[blk * 2 + 0] = mean;
        stats[blk * 2 + 1] = rsqrtf(var + 1e-5f);
    }
}

// ---------------------------------------------------------------------------
// Per-pixel spectral attention (unchanged from round 1)
// ---------------------------------------------------------------------------
__global__ __launch_bounds__(256) void attn_kernel(
    const float* __restrict__ qraw, const float* __restrict__ kraw, const float* __restrict__ vin,
    const float* __restrict__ stats,
    const float* __restrict__ gqg, const float* __restrict__ gqb,
    const float* __restrict__ gkg, const float* __restrict__ gkb,
    float* __restrict__ out)
{
    __shared__ float ksm[16 * 256];
    __shared__ float vsm[16 * 256];
    const int t = threadIdx.x;
    const int blk = blockIdx.x;
    const int b = blk >> 8;
    const int hw0 = (blk & 255) * 16;
    const size_t base = (size_t)b * PLANE + (size_t)t * HW_ + hw0;
    const int g = t >> 5;
    const int sg = (b * 8 + g) * 2;

    {
        float m = stats[64 + sg], r = stats[64 + sg + 1];
        float ga = r * gkg[t];
        float be = gkb[t] - m * ga;
        float kv[16];
        const float4* kp = (const float4*)(kraw + base);
#pragma unroll
        for (int i = 0; i < 4; i++) {
            float4 k4 = kp[i];
            kv[4 * i + 0] = k4.x * ga + be;
            kv[4 * i + 1] = k4.y * ga + be;
            kv[4 * i + 2] = k4.z * ga + be;
            kv[4 * i + 3] = k4.w * ga + be;
        }
#pragma unroll
        for (int p = 0; p < 16; p++) {
            float sk = kv[p] * kv[p];
#pragma unroll
            for (int mm = 1; mm < 32; mm <<= 1) sk += __shfl_xor(sk, mm);
            float inv = 1.f / fmaxf(sqrtf(sk), 1e-12f);
            ksm[p * 256 + t] = kv[p] * inv;
        }
    }
    {
        const float4* vp = (const float4*)(vin + base);
#pragma unroll
        for (int i = 0; i < 4; i++) {
            float4 v4 = vp[i];
            vsm[(4 * i + 0) * 256 + t] = v4.x;
            vsm[(4 * i + 1) * 256 + t] = v4.y;
            vsm[(4 * i + 2) * 256 + t] = v4.z;
            vsm[(4 * i + 3) * 256 + t] = v4.w;
        }
    }
    float an[16];
    {
        float m = stats[sg], r = stats[sg + 1];
        float ga = r * gqg[t];
        float be = gqb[t] - m * ga;
        float qv[16];
        const float4* qp = (const float4*)(qraw + base);
#pragma unroll
        for (int i = 0; i < 4; i++) {
            float4 q4 = qp[i];
            qv[4 * i + 0] = q4.x * ga + be;
            qv[4 * i + 1] = q4.y * ga + be;
            qv[4 * i + 2] = q4.z * ga + be;
            qv[4 * i + 3] = q4.w * ga + be;
        }
#pragma unroll
        for (int p = 0; p < 16; p++) {
            float sq = qv[p] * qv[p];
#pragma unroll
            for (int mm = 1; mm < 32; mm <<= 1) sq += __shfl_xor(sq, mm);
            float inv = 1.f / fmaxf(sqrtf(sq), 1e-12f);
            an[p] = qv[p] * inv * 0.17677669529663687f;
        }
    }
    __syncthreads();
    const int hbase = (t >> 5) * 32;
    float outp[16];
#pragma unroll
    for (int p = 0; p < 16; p++) {
        const float* ksp = ksm + p * 256 + hbase;
        const float* vsp = vsm + p * 256 + hbase;
        float a = an[p], num = 0.f, den = 0.f;
#pragma unroll
        for (int e = 0; e < 32; e++) {
            float w = __expf(a * ksp[e]);
            den += w;
            num += w * vsp[e];
        }
        outp[p] = num / den;
    }
    float4* op = (float4*)(out + base);
#pragma unroll
    for (int i = 0; i < 4; i++)
        op[i] = make_float4(outp[4 * i], outp[4 * i + 1], outp[4 * i + 2], outp[4 * i + 3]);
}

// ---------------------------------------------------------------------------
// Depthwise 3x3 stencils (unchanged from round 1)
// ---------------------------------------------------------------------------
__device__ __forceinline__ float gelu_exact(float v) {
    return 0.5f * v * (1.f + erff(v * 0.70710678118654752f));
}

__global__ __launch_bounds__(256) void dwconv1_kernel(
    const float* __restrict__ x, const float* __restrict__ w9,
    const float* __restrict__ bias, float* __restrict__ out)
{
    int idx = blockIdx.x * 256 + threadIdx.x;
    int xx = idx & 63, yy = (idx >> 6) & 63, c = (idx >> 12) & 255;
    const float* plane = x + (idx & ~4095);
    const float* wc = w9 + c * 9;
    float s = bias[c];
#pragma unroll
    for (int ky = 0; ky < 3; ky++) {
        int y2 = yy + ky - 1;
        if ((unsigned)y2 < 64u) {
#pragma unroll
            for (int kx = 0; kx < 3; kx++) {
                int x2 = xx + kx - 1;
                if ((unsigned)x2 < 64u) s += wc[ky * 3 + kx] * plane[y2 * 64 + x2];
            }
        }
    }
    out[idx] = gelu_exact(s);
}

__global__ __launch_bounds__(256) void dwconv2_add_kernel(
    const float* __restrict__ p1, const float* __restrict__ w9,
    const float* __restrict__ bias, float* __restrict__ io)
{
    int idx = blockIdx.x * 256 + threadIdx.x;
    int xx = idx & 63, yy = (idx >> 6) & 63, c = (idx >> 12) & 255;
    const float* plane = p1 + (idx & ~4095);
    const float* wc = w9 + c * 9;
    float s = bias[c];
#pragma unroll
    for (int ky = 0; ky < 3; ky++) {
        int y2 = yy + ky - 1;
        if ((unsigned)y2 < 64u) {
#pragma unroll
            for (int kx = 0; kx < 3; kx++) {
                int x2 = xx + kx - 1;
                if ((unsigned)x2 < 64u) s += wc[ky * 3 + kx] * plane[y2 * 64 + x2];
            }
        }
    }
    io[idx] += s;
}

// ---------------------------------------------------------------------------
// Final GroupNorm apply (unchanged)
// ---------------------------------------------------------------------------
__global__ __launch_bounds__(256) void gn_apply_kernel(
    float* __restrict__ y, const float* __restrict__ stats,
    const float* __restrict__ gamma, const float* __restrict__ beta)
{
    int i4 = blockIdx.x * 256 + threadIdx.x;
    int idx = i4 * 4;
    int c = (idx >> 12) & 255;
    int bg = ((idx >> 20) << 3) | (c >> 5);
    float mean = stats[128 + bg * 2], rstd = stats[128 + bg * 2 + 1];
    float ga = rstd * gamma[c], be = beta[c] - mean * ga;
    float4 v4 = *(float4*)&y[idx];
    v4.x = v4.x * ga + be;
    v4.y = v4.y * ga + be;
    v4.z = v4.z * ga + be;
    v4.w = v4.w * ga + be;
    *(float4*)&y[idx] = v4;
}

// ---------------------------------------------------------------------------
extern "C" void kernel_launch(void* const* d_in, const int* in_sizes, int n_in,
                              void* d_out, int out_size, void* d_ws, size_t ws_size,
                              hipStream_t stream)
{
    const float* x   = (const float*)d_in[0];
    const float* wq  = (const float*)d_in[1];
    const float* gqg = (const float*)d_in[2];
    const float* gqb = (const float*)d_in[3];
    const float* wk  = (const float*)d_in[4];
    const float* gkg = (const float*)d_in[5];
    const float* gkb = (const float*)d_in[6];
    const float* wv  = (const float*)d_in[7];
    const float* wp  = (const float*)d_in[8];
    const float* bp  = (const float*)d_in[9];
    const float* gpg = (const float*)d_in[10];
    const float* gpb = (const float*)d_in[11];
    const float* dw1 = (const float*)d_in[12];
    const float* db1 = (const float*)d_in[13];
    const float* dw2 = (const float*)d_in[14];
    const float* db2 = (const float*)d_in[15];
    float* out = (float*)d_out;

    float* ws   = (float*)d_ws;
    float* qraw = ws;                                 // 16 MB fp32 [c][n]
    float* kraw = ws + (size_t)4194304;               // 16 MB
    float* vbuf = ws + (size_t)2 * 4194304;           // 16 MB
    float* abuf = ws + (size_t)3 * 4194304;           // 16 MB
    float* pos1 = qraw;                               // reuse (attn already done)
    unsigned short* xT  = (unsigned short*)(ws + (size_t)4 * 4194304); // 8 MB bf16 [b][n][c]
    unsigned short* aT  = xT;                          // reuse after qkv gemm
    unsigned short* wbf = (unsigned short*)(ws + (size_t)4 * 4194304 + 2097152); // 512 KB
    float* stats = ws + (size_t)4 * 4194304 + 2097152 + 131072; // 192 floats

    dim3 blk(256);
    wcvt_kernel<<<dim3(1024), blk, 0, stream>>>(wq, wk, wv, wp, wbf);
    transpose_cvt_kernel<<<dim3(64, 4, 4), blk, 0, stream>>>(x, xT);
    gemm_qkv_mfma<<<dim3(32, 2, 12), blk, 0, stream>>>(wbf, xT, qraw, kraw, vbuf);
    gn_stats_kernel<<<dim3(64), blk, 0, stream>>>(qraw, kraw, stats);
    attn_kernel<<<dim3(1024), blk, 0, stream>>>(qraw, kraw, vbuf, stats,
                                                gqg, gqb, gkg, gkb, abuf);
    dwconv1_kernel<<<dim3(16384), blk, 0, stream>>>(x, dw1, db1, pos1);
    dwconv2_add_kernel<<<dim3(16384), blk, 0, stream>>>(pos1, dw2, db2, abuf);
    transpose_cvt_kernel<<<dim3(64, 4, 4), blk, 0, stream>>>(abuf, aT);
    gemm_out_mfma<<<dim3(32, 2, 4), blk, 0, stream>>>(wbf, aT, bp, out);
    gn_stats_kernel<<<dim3(32), blk, 0, stream>>>(out, out, stats + 128);
    gn_apply_kernel<<<dim3(4096), blk, 0, stream>>>(out, stats, gpg, gpb);
}

// Round 4
// 217.171 us; speedup vs baseline: 1.5613x; 1.1859x over previous
//
#include <hip/hip_runtime.h>
#include <math.h>
#include <stdint.h>

#define C_ 256
#define HW_ 4096
#define PLANE (C_*HW_)   // 1048576 elements per batch

typedef __attribute__((ext_vector_type(8))) short bf16x8;
typedef __attribute__((ext_vector_type(4))) float f32x4;

__device__ __forceinline__ unsigned short f2bf(float f) {
    union { float f; unsigned int u; } v; v.f = f;
    unsigned int r = v.u + 0x7fffu + ((v.u >> 16) & 1u);
    return (unsigned short)(r >> 16);
}

__device__ __forceinline__ void load_lds16(const void* g, void* l) {
    __builtin_amdgcn_global_load_lds(
        (const __attribute__((address_space(1))) unsigned int*)g,
        (__attribute__((address_space(3))) unsigned int*)l, 16, 0, 0);
}

// ---------------------------------------------------------------------------
// Weight convert: wq,wk,wv,wp (each 256x256 fp32, [o][c] K-contig) -> bf16
// ---------------------------------------------------------------------------
__global__ __launch_bounds__(256) void wcvt_kernel(
    const float* __restrict__ wq, const float* __restrict__ wk,
    const float* __restrict__ wv, const float* __restrict__ wp,
    unsigned short* __restrict__ dst)
{
    int idx = blockIdx.x * 256 + threadIdx.x;   // 262144 total
    const float* s = (idx < 65536) ? wq : (idx < 131072) ? wk
                   : (idx < 196608) ? wv : wp;
    dst[idx] = f2bf(s[idx & 65535]);
}

// ---------------------------------------------------------------------------
// Transpose + convert: src fp32 [b][256][4096] -> dst bf16 [b][4096][256]
// ---------------------------------------------------------------------------
__global__ __launch_bounds__(256) void transpose_cvt_kernel(
    const float* __restrict__ src, unsigned short* __restrict__ dst)
{
    __shared__ float tile[64][65];
    int b = blockIdx.z;
    const float* s = src + (size_t)b * PLANE;
    unsigned short* d = dst + (size_t)b * PLANE;
    int c0 = blockIdx.y * 64, n0 = blockIdx.x * 64;
    int t = threadIdx.x;
    int r = t >> 6, col = t & 63;
#pragma unroll
    for (int i = 0; i < 16; i++)
        tile[r + i * 4][col] = s[(size_t)(c0 + r + i * 4) * HW_ + n0 + col];
    __syncthreads();
#pragma unroll
    for (int i = 0; i < 16; i++)
        d[(size_t)(n0 + r + i * 4) * 256 + c0 + col] = f2bf(tile[col][r + i * 4]);
}

// ---------------------------------------------------------------------------
// Transpose + add attn(token-major) + convert: aT[n][c] = pos[c][n] + attn[n][c]
// ---------------------------------------------------------------------------
__global__ __launch_bounds__(256) void transpose_cvt_add_kernel(
    const float* __restrict__ pos, const float* __restrict__ attn,
    unsigned short* __restrict__ dst)
{
    __shared__ float tile[64][65];
    int b = blockIdx.z;
    const float* s = pos + (size_t)b * PLANE;
    const float* a = attn + (size_t)b * PLANE;
    unsigned short* d = dst + (size_t)b * PLANE;
    int c0 = blockIdx.y * 64, n0 = blockIdx.x * 64;
    int t = threadIdx.x;
    int r = t >> 6, col = t & 63;
#pragma unroll
    for (int i = 0; i < 16; i++)
        tile[r + i * 4][col] = s[(size_t)(c0 + r + i * 4) * HW_ + n0 + col];
    __syncthreads();
#pragma unroll
    for (int i = 0; i < 16; i++) {
        size_t o = (size_t)(n0 + r + i * 4) * 256 + c0 + col;
        d[o] = f2bf(tile[col][r + i * 4] + a[o]);
    }
}

// ---------------------------------------------------------------------------
// Unified MFMA GEMM: C[m][n] = sum_k A[m][k] * B[n][k]  (both K-contig bf16,
// ld 256). Y row stride ldy. Optional bias per m-row.
// 128x128 tile, BK=32, 4 waves x (4x4 frags of 16x16x32), global_load_lds.
// ---------------------------------------------------------------------------
template<bool BIAS>
__device__ __forceinline__ void mfma_gemm_body(
    const unsigned short* __restrict__ A,
    const unsigned short* __restrict__ Bm,
    const float* __restrict__ bias,
    float* __restrict__ Y, int ldy)
{
    __shared__ unsigned short As[128 * 32];
    __shared__ unsigned short Bs[128 * 32];
    const int t = threadIdx.x;
    const int lane = t & 63, wave = t >> 6;
    const int n0 = blockIdx.x * 128;
    const int m0 = blockIdx.y * 128;

    f32x4 acc[4][4];
#pragma unroll
    for (int i = 0; i < 4; i++)
#pragma unroll
        for (int j = 0; j < 4; j++) acc[i][j] = (f32x4)0.f;

    const int srow = wave * 32 + (lane >> 2);
    const int scol = (lane & 3) * 8;
    const unsigned short* ga = A  + (size_t)(m0 + srow) * 256 + scol;
    const unsigned short* gb = Bm + (size_t)(n0 + srow) * 256 + scol;
    unsigned short* la = As + (wave * 32) * 32;
    unsigned short* lb = Bs + (wave * 32) * 32;

    const int wm = wave >> 1, wn = wave & 1;
    const int fr = lane & 15, kg = lane >> 4;

    for (int k0 = 0; k0 < 256; k0 += 32) {
        if (k0) __syncthreads();
        load_lds16(ga + k0,             la);
        load_lds16(ga + k0 + 16 * 256,  la + 16 * 32);
        load_lds16(gb + k0,             lb);
        load_lds16(gb + k0 + 16 * 256,  lb + 16 * 32);
        __syncthreads();

        bf16x8 af[4], bfr[4];
#pragma unroll
        for (int i = 0; i < 4; i++) {
            af[i]  = *(const bf16x8*)(As + (wm * 64 + i * 16 + fr) * 32 + kg * 8);
            bfr[i] = *(const bf16x8*)(Bs + (wn * 64 + i * 16 + fr) * 32 + kg * 8);
        }
#pragma unroll
        for (int mi = 0; mi < 4; mi++)
#pragma unroll
            for (int ni = 0; ni < 4; ni++)
                acc[mi][ni] = __builtin_amdgcn_mfma_f32_16x16x32_bf16(
                    af[mi], bfr[ni], acc[mi][ni], 0, 0, 0);
    }

    const int cl = lane & 15, q = lane >> 4;
#pragma unroll
    for (int mi = 0; mi < 4; mi++) {
#pragma unroll
        for (int r = 0; r < 4; r++) {
            int grow = m0 + wm * 64 + mi * 16 + q * 4 + r;
            float bb = BIAS ? bias[grow] : 0.f;
#pragma unroll
            for (int ni = 0; ni < 4; ni++) {
                int gcol = n0 + wn * 64 + ni * 16 + cl;
                Y[(size_t)grow * ldy + gcol] = acc[mi][ni][r] + bb;
            }
        }
    }
}

// q/k/v token-major: C[token][outch]; grid (2, 32, 12)
__global__ __launch_bounds__(256) void gemm_qkv_mfma(
    const unsigned short* __restrict__ wbf, const unsigned short* __restrict__ xT,
    float* __restrict__ q, float* __restrict__ k, float* __restrict__ v)
{
    int z = blockIdx.z;
    int batch = z & 3, which = z >> 2;
    float* Y = (which == 0) ? q : (which == 1) ? k : v;
    mfma_gemm_body<false>(xT + (size_t)batch * PLANE, wbf + which * 65536,
                          nullptr, Y + (size_t)batch * PLANE, 256);
}

// final projection channel-major: C[outch][token]; grid (32, 2, 4)
__global__ __launch_bounds__(256) void gemm_out_mfma(
    const unsigned short* __restrict__ wbf, const unsigned short* __restrict__ aT,
    const float* __restrict__ bp, float* __restrict__ y)
{
    int batch = blockIdx.z;
    mfma_gemm_body<true>(wbf + 3 * 65536, aT + (size_t)batch * PLANE, bp,
                         y + (size_t)batch * PLANE, HW_);
}

// ---------------------------------------------------------------------------
// GroupNorm stats, token-major input [b][4096][256]: block per (tensor,b,g)
// ---------------------------------------------------------------------------
__global__ __launch_bounds__(256) void gn_stats_tok_kernel(
    const float* __restrict__ t0, const float* __restrict__ t1, float* __restrict__ stats)
{
    int blk = blockIdx.x;
    const float* src = (blk < 32) ? t0 : t1;
    int bg = blk & 31;
    const float* base = src + (size_t)(bg >> 3) * PLANE + (size_t)(bg & 7) * 32;
    int t = threadIdx.x;
    float s = 0.f, ss = 0.f;
    for (int i = 0; i < 16; i++) {
        const float4* p = (const float4*)(base + (size_t)(i * 256 + t) * 256);
#pragma unroll
        for (int j = 0; j < 8; j++) {
            float4 v4 = p[j];
            s  += v4.x + v4.y + v4.z + v4.w;
            ss += v4.x * v4.x + v4.y * v4.y + v4.z * v4.z + v4.w * v4.w;
        }
    }
#pragma unroll
    for (int off = 32; off >= 1; off >>= 1) {
        s  += __shfl_down(s, off);
        ss += __shfl_down(ss, off);
    }
    __shared__ float red[8];
    int wave = t >> 6;
    if ((t & 63) == 0) { red[wave * 2] = s; red[wave * 2 + 1] = ss; }
    __syncthreads();
    if (t == 0) {
        float S = 0.f, SS = 0.f;
        for (int w = 0; w < 4; w++) { S += red[w * 2]; SS += red[w * 2 + 1]; }
        float mean = S * (1.f / 131072.f);
        float var  = SS * (1.f / 131072.f) - mean * mean;
        stats[blk * 2 + 0] = mean;
        stats[blk * 2 + 1] = rsqrtf(var + 1e-5f);
    }
}

// ---------------------------------------------------------------------------
// GroupNorm stats, channel-major (for final output GN)
// ---------------------------------------------------------------------------
__global__ __launch_bounds__(256) void gn_stats_kernel(
    const float* __restrict__ t0, float* __restrict__ stats)
{
    int blk = blockIdx.x;
    int bg = blk & 31;
    const float* base = t0 + (size_t)(bg >> 3) * PLANE + (size_t)(bg & 7) * 32 * HW_;
    int t = threadIdx.x;
    float s = 0.f, ss = 0.f;
    for (int c = 0; c < 32; c++) {
        const float* row = base + (size_t)c * HW_;
#pragma unroll
        for (int i = 0; i < 4; i++) {
            float4 v4 = *(const float4*)&row[(i * 256 + t) * 4];
            s  += v4.x + v4.y + v4.z + v4.w;
            ss += v4.x * v4.x + v4.y * v4.y + v4.z * v4.z + v4.w * v4.w;
        }
    }
#pragma unroll
    for (int off = 32; off >= 1; off >>= 1) {
        s  += __shfl_down(s, off);
        ss += __shfl_down(ss, off);
    }
    __shared__ float red[8];
    int wave = t >> 6;
    if ((t & 63) == 0) { red[wave * 2] = s; red[wave * 2 + 1] = ss; }
    __syncthreads();
    if (t == 0) {
        float S = 0.f, SS = 0.f;
        for (int w = 0; w < 4; w++) { S += red[w * 2]; SS += red[w * 2 + 1]; }
        float mean = S * (1.f / 131072.f);
        float var  = SS * (1.f / 131072.f) - mean * mean;
        stats[blk * 2 + 0] = mean;
        stats[blk * 2 + 1] = rsqrtf(var + 1e-5f);
    }
}

// ---------------------------------------------------------------------------
// Attention, token-major. Thread = one (pixel, head): everything in registers.
// group == head (both 32 channels). out[d] = sum_e exp2(a_d*kn_e)*v_e / den
// ---------------------------------------------------------------------------
__global__ __launch_bounds__(256) void attn_tok_kernel(
    const float* __restrict__ qtok, const float* __restrict__ ktok,
    const float* __restrict__ vtok, const float* __restrict__ stats,
    const float* __restrict__ gqg, const float* __restrict__ gqb,
    const float* __restrict__ gkg, const float* __restrict__ gkb,
    float* __restrict__ out)
{
    __shared__ float sqg[256], sqb[256], skg[256], skb[256];
    const int t = threadIdx.x;
    sqg[t] = gqg[t]; sqb[t] = gqb[t]; skg[t] = gkg[t]; skb[t] = gkb[t];
    __syncthreads();

    const int h = t & 7;
    const int pix = blockIdx.x * 32 + (t >> 3);   // 0..16383
    const int b = pix >> 12;
    const size_t base = (size_t)pix * 256 + h * 32;
    const int sg = (b * 8 + h) * 2;
    const float K2 = 0.17677669529663687f * 1.4426950408889634f; // scale*log2e

    float a[32], kn[32], vv[32];

    // Q: load + GN affine + normalize -> a[] (scaled for exp2)
    {
        float m = stats[sg], r = stats[sg + 1];
        float qv[32], ssum = 0.f;
        const float4* qp = (const float4*)(qtok + base);
#pragma unroll
        for (int i = 0; i < 8; i++) {
            float4 q4 = qp[i];
            float g0 = r * sqg[h * 32 + 4 * i + 0], b0 = sqb[h * 32 + 4 * i + 0];
            float g1 = r * sqg[h * 32 + 4 * i + 1], b1 = sqb[h * 32 + 4 * i + 1];
            float g2 = r * sqg[h * 32 + 4 * i + 2], b2 = sqb[h * 32 + 4 * i + 2];
            float g3 = r * sqg[h * 32 + 4 * i + 3], b3 = sqb[h * 32 + 4 * i + 3];
            qv[4 * i + 0] = (q4.x - m) * g0 + b0;
            qv[4 * i + 1] = (q4.y - m) * g1 + b1;
            qv[4 * i + 2] = (q4.z - m) * g2 + b2;
            qv[4 * i + 3] = (q4.w - m) * g3 + b3;
        }
#pragma unroll
        for (int j = 0; j < 32; j++) ssum += qv[j] * qv[j];
        float inv = K2 / fmaxf(sqrtf(ssum), 1e-12f);
#pragma unroll
        for (int j = 0; j < 32; j++) a[j] = qv[j] * inv;
    }
    // K: load + GN affine + normalize -> kn[]
    {
        float m = stats[64 + sg], r = stats[64 + sg + 1];
        float ssum = 0.f;
        const float4* kp = (const float4*)(ktok + base);
#pragma unroll
        for (int i = 0; i < 8; i++) {
            float4 k4 = kp[i];
            float g0 = r * skg[h * 32 + 4 * i + 0], b0 = skb[h * 32 + 4 * i + 0];
            float g1 = r * skg[h * 32 + 4 * i + 1], b1 = skb[h * 32 + 4 * i + 1];
            float g2 = r * skg[h * 32 + 4 * i + 2], b2 = skb[h * 32 + 4 * i + 2];
            float g3 = r * skg[h * 32 + 4 * i + 3], b3 = skb[h * 32 + 4 * i + 3];
            kn[4 * i + 0] = (k4.x - m) * g0 + b0;
            kn[4 * i + 1] = (k4.y - m) * g1 + b1;
            kn[4 * i + 2] = (k4.z - m) * g2 + b2;
            kn[4 * i + 3] = (k4.w - m) * g3 + b3;
        }
#pragma unroll
        for (int j = 0; j < 32; j++) ssum += kn[j] * kn[j];
        float inv = 1.f / fmaxf(sqrtf(ssum), 1e-12f);
#pragma unroll
        for (int j = 0; j < 32; j++) kn[j] *= inv;
    }
    // V
    {
        const float4* vp = (const float4*)(vtok + base);
#pragma unroll
        for (int i = 0; i < 8; i++) {
            float4 v4 = vp[i];
            vv[4 * i + 0] = v4.x; vv[4 * i + 1] = v4.y;
            vv[4 * i + 2] = v4.z; vv[4 * i + 3] = v4.w;
        }
    }
    // 32x32 softmax-weighted sum, 4 outputs at a time
    float4* op = (float4*)(out + base);
#pragma unroll
    for (int di = 0; di < 8; di++) {
        float o[4];
#pragma unroll
        for (int dd = 0; dd < 4; dd++) {
            float ad = a[di * 4 + dd];
            float num = 0.f, den = 0.f;
#pragma unroll
            for (int e = 0; e < 32; e++) {
                float w = __builtin_amdgcn_exp2f(ad * kn[e]);
                num = fmaf(w, vv[e], num);
                den += w;
            }
            o[dd] = num / den;
        }
        op[di] = make_float4(o[0], o[1], o[2], o[3]);
    }
}

// ---------------------------------------------------------------------------
// Fused depthwise 3x3 -> GELU -> depthwise 3x3. One (b,c) plane per block.
// conv2 pads the GELU output with zeros (reference 'SAME' semantics).
// ---------------------------------------------------------------------------
__device__ __forceinline__ float gelu_exact(float v) {
    return 0.5f * v * (1.f + erff(v * 0.70710678118654752f));
}

__global__ __launch_bounds__(256) void dwconv_fused_kernel(
    const float* __restrict__ x,
    const float* __restrict__ dw1, const float* __restrict__ db1,
    const float* __restrict__ dw2, const float* __restrict__ db2,
    float* __restrict__ pos)
{
    __shared__ float xs[66 * 68];   // rows -1..64, cols -1..64 (stride 68)
    __shared__ float ps[66 * 68];   // gelu(conv1) rows -1..64 (halo = 0)
    const int bc = blockIdx.x;      // b*256 + c
    const int c = bc & 255;
    const int t = threadIdx.x;
    const float* plane = x + (size_t)bc * 4096;

    float w1[9], w2[9];
#pragma unroll
    for (int i = 0; i < 9; i++) { w1[i] = dw1[c * 9 + i]; w2[i] = dw2[c * 9 + i]; }
    const float b1 = db1[c], b2 = db2[c];

    // stage x with zero halo of 1
    for (int i = t; i < 66 * 66; i += 256) {
        int r = i / 66, cc = i - r * 66;
        int gr = r - 1, gc = cc - 1;
        float v = 0.f;
        if ((unsigned)gr < 64u && (unsigned)gc < 64u) v = plane[gr * 64 + gc];
        xs[r * 68 + cc] = v;
    }
    __syncthreads();

    // conv1 + gelu; zero outside plane (conv2's zero padding)
    for (int i = t; i < 66 * 66; i += 256) {
        int pr = i / 66, pc = i - pr * 66;
        int gr = pr - 1, gc = pc - 1;
        float val = 0.f;
        if ((unsigned)gr < 64u && (unsigned)gc < 64u) {
            float s = b1;
#pragma unroll
            for (int ky = 0; ky < 3; ky++)
#pragma unroll
                for (int kx = 0; kx < 3; kx++)
                    s += w1[ky * 3 + kx] * xs[(gr + ky) * 68 + (gc + kx)];
            val = gelu_exact(s);
        }
        ps[pr * 68 + pc] = val;
    }
    __syncthreads();

    // conv2
    for (int i = t; i < 4096; i += 256) {
        int orow = i >> 6, ocol = i & 63;
        float s = b2;
#pragma unroll
        for (int ky = 0; ky < 3; ky++)
#pragma unroll
            for (int kx = 0; kx < 3; kx++)
                s += w2[ky * 3 + kx] * ps[(orow + ky) * 68 + (ocol + kx)];
        pos[(size_t)bc * 4096 + i] = s;
    }
}

// ---------------------------------------------------------------------------
// Final GroupNorm apply (in place on d_out)
// ---------------------------------------------------------------------------
__global__ __launch_bounds__(256) void gn_apply_kernel(
    float* __restrict__ y, const float* __restrict__ stats,
    const float* __restrict__ gamma, const float* __restrict__ beta)
{
    int i4 = blockIdx.x * 256 + threadIdx.x;
    int idx = i4 * 4;
    int c = (idx >> 12) & 255;
    int bg = ((idx >> 20) << 3) | (c >> 5);
    float mean = stats[128 + bg * 2], rstd = stats[128 + bg * 2 + 1];
    float ga = rstd * gamma[c], be = beta[c] - mean * ga;
    float4 v4 = *(float4*)&y[idx];
    v4.x = v4.x * ga + be;
    v4.y = v4.y * ga + be;
    v4.z = v4.z * ga + be;
    v4.w = v4.w * ga + be;
    *(float4*)&y[idx] = v4;
}

// ---------------------------------------------------------------------------
extern "C" void kernel_launch(void* const* d_in, const int* in_sizes, int n_in,
                              void* d_out, int out_size, void* d_ws, size_t ws_size,
                              hipStream_t stream)
{
    const float* x   = (const float*)d_in[0];
    const float* wq  = (const float*)d_in[1];
    const float* gqg = (const float*)d_in[2];
    const float* gqb = (const float*)d_in[3];
    const float* wk  = (const float*)d_in[4];
    const float* gkg = (const float*)d_in[5];
    const float* gkb = (const float*)d_in[6];
    const float* wv  = (const float*)d_in[7];
    const float* wp  = (const float*)d_in[8];
    const float* bp  = (const float*)d_in[9];
    const float* gpg = (const float*)d_in[10];
    const float* gpb = (const float*)d_in[11];
    const float* dw1 = (const float*)d_in[12];
    const float* db1 = (const float*)d_in[13];
    const float* dw2 = (const float*)d_in[14];
    const float* db2 = (const float*)d_in[15];
    float* out = (float*)d_out;

    float* ws   = (float*)d_ws;
    float* qtok = ws;                                 // 16 MB fp32 [n][c]
    float* ktok = ws + (size_t)4194304;               // 16 MB
    float* vtok = ws + (size_t)2 * 4194304;           // 16 MB
    float* atok = ws + (size_t)3 * 4194304;           // 16 MB [n][c]
    float* pos  = qtok;                               // reuse (attn consumed q)
    unsigned short* xT  = (unsigned short*)(ws + (size_t)4 * 4194304); // 8 MB bf16 [n][c]
    unsigned short* aT  = xT;                          // reuse after qkv gemm
    unsigned short* wbf = (unsigned short*)(ws + (size_t)4 * 4194304 + 2097152); // 512 KB
    float* stats = ws + (size_t)4 * 4194304 + 2097152 + 131072; // 192 floats

    dim3 blk(256);
    wcvt_kernel<<<dim3(1024), blk, 0, stream>>>(wq, wk, wv, wp, wbf);
    transpose_cvt_kernel<<<dim3(64, 4, 4), blk, 0, stream>>>(x, xT);
    gemm_qkv_mfma<<<dim3(2, 32, 12), blk, 0, stream>>>(wbf, xT, qtok, ktok, vtok);
    gn_stats_tok_kernel<<<dim3(64), blk, 0, stream>>>(qtok, ktok, stats);
    attn_tok_kernel<<<dim3(512), blk, 0, stream>>>(qtok, ktok, vtok, stats,
                                                   gqg, gqb, gkg, gkb, atok);
    dwconv_fused_kernel<<<dim3(1024), blk, 0, stream>>>(x, dw1, db1, dw2, db2, pos);
    transpose_cvt_add_kernel<<<dim3(64, 4, 4), blk, 0, stream>>>(pos, atok, aT);
    gemm_out_mfma<<<dim3(32, 2, 4), blk, 0, stream>>>(wbf, aT, bp, out);
    gn_stats_kernel<<<dim3(32), blk, 0, stream>>>(out, stats + 128);
    gn_apply_kernel<<<dim3(4096), blk, 0, stream>>>(out, stats, gpg, gpb);
}